// Round 1
// baseline (983.120 us; speedup 1.0000x reference)
//
#include <hip/hip_runtime.h>

// GCN layer: out = D^{-1/2} A D^{-1/2} X  (index == arange(N) => scatter is identity)
// N=100000, E=6400000, D=32. All integer inputs arrive as int32 per harness contract.

#define FEAT_D 32

__global__ void degree_kernel(const int* __restrict__ rows,
                              const float* __restrict__ vals,
                              float* __restrict__ rowsum, int E) {
    int i = blockIdx.x * blockDim.x + threadIdx.x;
    int stride = gridDim.x * blockDim.x;
    for (; i < E; i += stride) {
        atomicAdd(&rowsum[rows[i]], vals[i]);
    }
}

__global__ void dinv_kernel(const float* __restrict__ rowsum,
                            float* __restrict__ dinv, int n) {
    int i = blockIdx.x * blockDim.x + threadIdx.x;
    if (i < n) {
        float r = rowsum[i];
        dinv[i] = (r > 0.0f) ? rsqrtf(r) : 0.0f;
    }
}

// One thread per (edge, dim). 32 consecutive threads share an edge:
//  - feature gather is one coalesced 128B line per edge
//  - rows/cols/vals loads are same-address within the 32-lane group (HW broadcast)
__global__ void spmm_kernel(const int* __restrict__ rows,
                            const int* __restrict__ cols,
                            const float* __restrict__ vals,
                            const float* __restrict__ dinv,
                            const float* __restrict__ feat,
                            float* __restrict__ out, int E) {
    long long tid = (long long)blockIdx.x * blockDim.x + threadIdx.x;
    long long total = (long long)E * FEAT_D;
    long long stride = (long long)gridDim.x * blockDim.x;
    for (; tid < total; tid += stride) {
        int e = (int)(tid >> 5);
        int d = (int)(tid & 31);
        int r = rows[e];
        int c = cols[e];
        float w = dinv[r] * vals[e] * dinv[c];
        atomicAdd(&out[(long long)r * FEAT_D + d], w * feat[(long long)c * FEAT_D + d]);
    }
}

extern "C" void kernel_launch(void* const* d_in, const int* in_sizes, int n_in,
                              void* d_out, int out_size, void* d_ws, size_t ws_size,
                              hipStream_t stream) {
    const float* features = (const float*)d_in[0];
    const int*   adj_rows = (const int*)d_in[1];
    const int*   adj_cols = (const int*)d_in[2];
    const float* adj_vals = (const float*)d_in[3];
    // d_in[4] = index == arange(N): scatter is identity, unused.

    float* out = (float*)d_out;
    int E = in_sizes[1];
    int n = in_sizes[4];

    float* rowsum = (float*)d_ws;
    float* dinv   = rowsum + n;

    hipMemsetAsync(rowsum, 0, (size_t)n * sizeof(float), stream);
    hipMemsetAsync(out, 0, (size_t)out_size * sizeof(float), stream);

    // degree histogram
    {
        int block = 256;
        int grid  = (E + block - 1) / block;
        if (grid > 8192) grid = 8192;
        degree_kernel<<<grid, block, 0, stream>>>(adj_rows, adj_vals, rowsum, E);
    }
    // d^{-1/2}
    {
        int block = 256;
        int grid  = (n + block - 1) / block;
        dinv_kernel<<<grid, block, 0, stream>>>(rowsum, dinv, n);
    }
    // SpMM with fused normalization
    {
        int block = 256;
        long long total = (long long)E * FEAT_D;
        long long gridl = (total + block - 1) / block;
        int grid = (gridl > 8192) ? 8192 : (int)gridl;
        spmm_kernel<<<grid, block, 0, stream>>>(adj_rows, adj_cols, adj_vals,
                                                dinv, features, out, E);
    }
}